// Round 6
// baseline (97.798 us; speedup 1.0000x reference)
//
#include <hip/hip_runtime.h>
#include <hip/hip_fp16.h>
#include <stdint.h>

// ---------------------------------------------------------------------------
// BareKANLayer: out[b,o] = sum_d PCHIP_interp(x[b,d]; coeffs[o,d,:]) + bias[o]
// B=8192, O=64, D=64, K=64, grid [-2,2], h = 4/63.
//
// Table (unchanged): per (d, interval i, o) cubic coeffs packed fp16 in uint2;
// row 63 = linear right-extrapolation row; left extrapolation reuses row 0.
// T[d][i][o], 32 KB/slice, 2 MB at ws+0.
//
// R6: R4/R5 showed main pinned at ~16 us regardless of compute structure ->
// the 268 MB random-row L2 gather stream is the bottleneck (~32 B/cyc/CU
// L1-miss path). kan_part stages d-slices into LDS (double-buffered) and
// gathers rows from LDS (~85 B/cyc/CU); block = 256 b x 4 d, grid 512
// (32 b-sets x 16 d-parts), partials in ws + tiny reduce kernel.
// ---------------------------------------------------------------------------

typedef _Float16 half2v __attribute__((ext_vector_type(2)));

#if defined(__has_builtin)
#if __has_builtin(__builtin_amdgcn_fdot2)
#define HAS_FDOT2 1
#endif
#if __has_builtin(__builtin_amdgcn_global_load_lds)
#define HAS_GLL 1
#endif
#endif

__device__ __forceinline__ uint32_t h16(float f) {
    return (uint32_t)__half_as_ushort(__float2half(f));   // RNE cvt
}

__device__ __forceinline__ float dot2acc(uint32_t a_bits, uint32_t b_bits, float acc) {
    half2v a = __builtin_bit_cast(half2v, a_bits);
    half2v b = __builtin_bit_cast(half2v, b_bits);
#ifdef HAS_FDOT2
    return __builtin_amdgcn_fdot2(a, b, acc, false);
#else
    return acc + (float)a.x * (float)b.x + (float)a.y * (float)b.y;
#endif
}

// Grid: 256 blocks (d = bx>>2, o-quarter = bx&3), 256 threads.
__global__ void build_table(const float* __restrict__ coeffs, uint2* __restrict__ T) {
    const float hf = 4.0f / 63.0f;
    const float inv_hf = 63.0f / 4.0f;   // 15.75 exact in fp32
    int d  = blockIdx.x >> 2;
    int ob = (blockIdx.x & 3) << 4;      // base of this block's 16 o's
    __shared__ float Y[16][65];          // +1 pad: conflict-free
    int t = threadIdx.x;
    {
        int ol = t >> 4;                 // 0..15  (o local)
        int k4 = (t & 15) << 2;          // 0,4,...,60
        const float* src = coeffs + (size_t)(ob + ol) * 4096 + d * 64 + k4;
        float4 v = *(const float4*)src;  // 16B aligned
        Y[ol][k4 + 0] = v.x; Y[ol][k4 + 1] = v.y;
        Y[ol][k4 + 2] = v.z; Y[ol][k4 + 3] = v.w;
    }
    __syncthreads();
    for (int c = t; c < 1024; c += 256) {
        int ol = c & 15;
        int i  = c >> 4;                 // 0..63 (63 = linear extrapolation row)
        const float* Yr = Y[ol];
        auto delt = [&](int k) -> float { return (Yr[k + 1] - Yr[k]) * inv_hf; };
        auto endslope = [&](float a, float b) -> float {
            float de = (3.0f * a - b) * 0.5f;
            de = (de * a <= 0.0f) ? 0.0f : de;
            de = ((a * b < 0.0f) && (fabsf(de) > 3.0f * fabsf(a))) ? 3.0f * a : de;
            return de;
        };
        auto slope = [&](int k) -> float {
            if (k == 0)  return endslope(delt(0), delt(1));
            if (k == 63) return endslope(delt(62), delt(61));
            float dp = delt(k - 1), dn = delt(k);
            return (dp * dn > 0.0f) ? (2.0f * dp * dn) / (dp + dn + 1e-12f) : 0.0f;
        };
        uint2 pk;
        if (i < 63) {
            float y0 = Yr[i], y1 = Yr[i + 1];
            float di = slope(i), dj = slope(i + 1);
            float c0 = y0;
            float c1 = hf * di;
            float c2 = 3.0f * (y1 - y0) - hf * (2.0f * di + dj);
            float c3 = 2.0f * (y0 - y1) + hf * (di + dj);
            pk.x = (h16(c1) << 16) | h16(c0);
            pk.y = (h16(c3) << 16) | h16(c2);
        } else {
            float yN = Yr[63];
            float dN = slope(63);
            pk.x = (h16(hf * dN) << 16) | h16(yN);
            pk.y = 0u;
        }
        T[(size_t)d * 4096 + i * 64 + (ob + ol)] = pk;
    }
}

// Stage one 32 KB d-slice into LDS. 256 threads x 16 B x 8 chunks.
__device__ __forceinline__ void stage_slice(const char* __restrict__ gsrc,
                                            uint2* __restrict__ ldst, int t) {
#ifdef HAS_GLL
    typedef const __attribute__((address_space(1))) uint32_t* gp_t;
    typedef __attribute__((address_space(3))) uint32_t* lp_t;
    char* l = (char*)ldst;
    #pragma unroll
    for (int k = 0; k < 8; ++k) {
        __builtin_amdgcn_global_load_lds((gp_t)(gsrc + k * 4096 + t * 16),
                                         (lp_t)(l + k * 4096 + t * 16), 16, 0, 0);
    }
#else
    const uint4* g = (const uint4*)gsrc;
    uint4* l = (uint4*)ldst;
    #pragma unroll
    for (int k = 0; k < 8; ++k) l[k * 256 + t] = g[k * 256 + t];
#endif
}

// Grid: 512 blocks x 256 threads (4 waves). Block = (b-set bs = bx&31 -> 256
// b's, d-part dp = bx>>5 -> 4 d's). Wave w owns b's [bs*256+w*64, +64);
// record for b sits in lane (b&63) of that wave. lane = o in gather phase.
__global__ void __launch_bounds__(256) kan_part(const float* __restrict__ x,
                                                const char* __restrict__ Tb,
                                                float* __restrict__ partial) {
    __shared__ uint2 buf[2][4096];       // 2 x 32 KB double buffer
    int t    = threadIdx.x;
    int lane = t & 63;
    int w    = t >> 6;
    int bs   = blockIdx.x & 31;
    int dp   = blockIdx.x >> 5;
    int b    = bs * 256 + t;

    // ---- records for (b, d = dp*4 + j), j=0..3, kept in VGPRs ----
    uint32_t rwa[4], rwb[4], roff[4];
    {
        float4 xv4 = *(const float4*)(x + (size_t)b * 64 + dp * 4);   // 16B aligned
        float xs[4] = {xv4.x, xv4.y, xv4.z, xv4.w};
        #pragma unroll
        for (int j = 0; j < 4; ++j) {
            float xv = xs[j];
            float tt = (xv + 2.0f) * 15.75f;
            int i = (int)floorf(tt);
            i = i < 0 ? 0 : (i > 62 ? 62 : i);
            float u = tt - (float)i;
            float w1, w2, w3; uint32_t off;
            if (xv < -2.0f)      { w1 = tt;         w2 = 0.f;   w3 = 0.f;    off = 0u; }
            else if (xv > 2.0f)  { w1 = tt - 63.0f; w2 = 0.f;   w3 = 0.f;    off = 63u << 9; }
            else                 { w1 = u;          w2 = u * u; w3 = w2 * u; off = (uint32_t)i << 9; }
            rwa[j]  = (h16(w1) << 16) | 0x3C00u;     // h2(1.0, w1)
            rwb[j]  = (h16(w3) << 16) | h16(w2);     // h2(w2, w3)
            roff[j] = off;                           // byte offset of row in slice
        }
    }

    float acc[64];
    #pragma unroll
    for (int bb = 0; bb < 64; ++bb) acc[bb] = 0.0f;

    // ---- stage slice 0, then loop: prefetch j+1 while gathering j ----
    stage_slice(Tb + (size_t)(dp * 4 + 0) * 32768, buf[0], t);
    __syncthreads();

    int laneoff = lane << 3;
    #pragma unroll
    for (int j = 0; j < 4; ++j) {
        if (j < 3)
            stage_slice(Tb + (size_t)(dp * 4 + j + 1) * 32768, buf[(j + 1) & 1], t);
        const char* sl = (const char*)buf[j & 1];
        #pragma unroll
        for (int bb = 0; bb < 64; ++bb) {
            uint32_t off = (uint32_t)__builtin_amdgcn_readlane((int)roff[j], bb);
            uint32_t wa  = (uint32_t)__builtin_amdgcn_readlane((int)rwa[j],  bb);
            uint32_t wb  = (uint32_t)__builtin_amdgcn_readlane((int)rwb[j],  bb);
            uint2 c = *(const uint2*)(sl + off + laneoff);   // ds_read_b64, conflict-free
            acc[bb] = dot2acc(wb, c.y, dot2acc(wa, c.x, acc[bb]));
        }
        __syncthreads();   // staging j+1 drained; buf[j&1] free for reuse
    }

    // ---- write partials: partial[dp][b][o], coalesced ----
    float* pbase = partial + ((size_t)dp * 8192 + bs * 256 + w * 64) * 64 + lane;
    #pragma unroll
    for (int bb = 0; bb < 64; ++bb) pbase[bb * 64] = acc[bb];
}

// Grid: 2048 blocks x 256 threads. out[b,o] = bias[o] + sum_p partial[p][b][o].
__global__ void __launch_bounds__(256) kan_reduce(const float* __restrict__ partial,
                                                  const float* __restrict__ bias,
                                                  float* __restrict__ out) {
    int id = blockIdx.x * 256 + threadIdx.x;   // 0 .. 524287
    float s = bias[id & 63];
    #pragma unroll
    for (int p = 0; p < 16; ++p) s += partial[(size_t)p * 524288 + id];
    out[id] = s;
}

extern "C" void kernel_launch(void* const* d_in, const int* in_sizes, int n_in,
                              void* d_out, int out_size, void* d_ws, size_t ws_size,
                              hipStream_t stream) {
    const float* x      = (const float*)d_in[0];   // [8192, 64]
    const float* coeffs = (const float*)d_in[1];   // [64, 64, 64]
    const float* bias   = (const float*)d_in[2];   // [64]
    float* out = (float*)d_out;                    // [8192, 64]

    uint2* T       = (uint2*)d_ws;                           // 2 MB table at ws+0
    float* partial = (float*)((char*)d_ws + (4u << 20));     // 32 MB partials at ws+4MB

    build_table<<<dim3(256), dim3(256), 0, stream>>>(coeffs, T);
    kan_part<<<dim3(512), dim3(256), 0, stream>>>(x, (const char*)d_ws, partial);
    kan_reduce<<<dim3(2048), dim3(256), 0, stream>>>(partial, bias, out);
}